// Round 2
// baseline (734.359 us; speedup 1.0000x reference)
//
#include <hip/hip_runtime.h>
#include <hip/hip_cooperative_groups.h>
#include <math.h>

namespace cg = cooperative_groups;

#define N_NODES 256
#define T_DIM   30000
#define H_DIM   512
#define L_DIM   256

#define KC      480   // per-split K chunk (mult of 16; 64*480 >= 30000)
#define SPLITK  64

// ---------------- P = I + C ----------------
__global__ void k_init_P(float* P) {
    int t = blockIdx.x * blockDim.x + threadIdx.x; // 65536 threads
    P[t] = ((t >> 8) == (t & 255)) ? 1.0f : 0.0f;
}

__global__ void k_count_edges(const int* __restrict__ idx, int E, float* P) {
    int e = blockIdx.x * blockDim.x + threadIdx.x;
    if (e < E) {
        int s = idx[e];
        int d = idx[E + e];
        atomicAdd(&P[d * N_NODES + s], 1.0f);
    }
}

__global__ void k_zero(float* p, int n) {
    int t = blockIdx.x * blockDim.x + threadIdx.x;
    if (t < n) p[t] = 0.0f;
}

// ---------------- big GEMM: Y1 = x @ Ws1a ----------------
// x [256,30000] row-major, W [30000,512] row-major.
// grid (4,2,SPLITK): 128x128 output tile per block, K split.
template<bool ATOMIC>
__global__ __launch_bounds__(256)
void k_gemm_big(const float* __restrict__ x, const float* __restrict__ W,
                float* __restrict__ outp) {
    __shared__ float xs[16 * 140]; // [k][r] transposed, pad 140
    __shared__ float ws[16 * 132]; // [k][c], pad 132

    const int t  = threadIdx.x;
    const int bx = blockIdx.x;   // col tile 0..3
    const int by = blockIdx.y;   // row tile 0..1
    const int z  = blockIdx.z;   // K split 0..SPLITK-1
    const int rowBase = by * 128;
    const int colBase = bx * 128;
    const int kb0  = z * KC;
    const int kend = min(kb0 + KC, T_DIM);
    const int nchunk = (kend > kb0) ? ((kend - kb0) >> 4) : 0;

    const int lr  = t >> 2;          // 0..63 (row for x load)
    const int lkq = (t & 3) * 4;     // 0,4,8,12 (k offset for x load)
    const int wkk = t >> 5;          // 0..7 (k row for W load)
    const int wcq = (t & 31) * 4;    // 0..124 (col offset for W load)
    const int tx  = t & 15, ty = t >> 4;

    float acc[8][8];
    #pragma unroll
    for (int i = 0; i < 8; ++i)
        #pragma unroll
        for (int j = 0; j < 8; ++j) acc[i][j] = 0.0f;

    if (nchunk > 0) {
        float4 xa, xb, wa, wb;
        {   // prefetch chunk 0
            const float* xp = x + (size_t)(rowBase + lr) * T_DIM + kb0 + lkq;
            xa = *(const float4*)xp;
            xb = *(const float4*)(xp + (size_t)64 * T_DIM);
            const float* wp = W + (size_t)(kb0 + wkk) * H_DIM + colBase + wcq;
            wa = *(const float4*)wp;
            wb = *(const float4*)(wp + 8 * H_DIM);
        }

        for (int c = 0; c < nchunk; ++c) {
            __syncthreads();
            xs[(lkq + 0) * 140 + lr] = xa.x;
            xs[(lkq + 1) * 140 + lr] = xa.y;
            xs[(lkq + 2) * 140 + lr] = xa.z;
            xs[(lkq + 3) * 140 + lr] = xa.w;
            xs[(lkq + 0) * 140 + lr + 64] = xb.x;
            xs[(lkq + 1) * 140 + lr + 64] = xb.y;
            xs[(lkq + 2) * 140 + lr + 64] = xb.z;
            xs[(lkq + 3) * 140 + lr + 64] = xb.w;
            *(float4*)&ws[wkk * 132 + wcq]       = wa;
            *(float4*)&ws[(wkk + 8) * 132 + wcq] = wb;
            __syncthreads();

            if (c + 1 < nchunk) {   // prefetch next chunk into regs
                int kb = kb0 + (c + 1) * 16;
                const float* xp = x + (size_t)(rowBase + lr) * T_DIM + kb + lkq;
                xa = *(const float4*)xp;
                xb = *(const float4*)(xp + (size_t)64 * T_DIM);
                const float* wp = W + (size_t)(kb + wkk) * H_DIM + colBase + wcq;
                wa = *(const float4*)wp;
                wb = *(const float4*)(wp + 8 * H_DIM);
            }

            #pragma unroll
            for (int kk = 0; kk < 16; ++kk) {
                float a[8], b[8];
                *(float4*)&a[0] = *(const float4*)&xs[kk * 140 + ty * 8];
                *(float4*)&a[4] = *(const float4*)&xs[kk * 140 + ty * 8 + 4];
                *(float4*)&b[0] = *(const float4*)&ws[kk * 132 + tx * 8];
                *(float4*)&b[4] = *(const float4*)&ws[kk * 132 + tx * 8 + 4];
                #pragma unroll
                for (int i = 0; i < 8; ++i)
                    #pragma unroll
                    for (int j = 0; j < 8; ++j)
                        acc[i][j] = fmaf(a[i], b[j], acc[i][j]);
            }
        }
    }

    if (ATOMIC) {
        if (nchunk == 0) return;
        #pragma unroll
        for (int i = 0; i < 8; ++i) {
            int r = rowBase + ty * 8 + i;
            #pragma unroll
            for (int j = 0; j < 8; ++j)
                atomicAdd(&outp[r * H_DIM + colBase + tx * 8 + j], acc[i][j]);
        }
    } else {
        float* op = outp + (size_t)z * (N_NODES * H_DIM);
        #pragma unroll
        for (int i = 0; i < 8; ++i) {
            int r = rowBase + ty * 8 + i;
            *(float4*)&op[r * H_DIM + colBase + tx * 8]     = *(float4*)&acc[i][0];
            *(float4*)&op[r * H_DIM + colBase + tx * 8 + 4] = *(float4*)&acc[i][4];
        }
    }
}

// ---------------- cooperative chain kernel ----------------
struct ChainArgs {
    const float* P;
    const float* Y1p;
    float* Y1;
    float* bufA;
    float* bufB;
    float* feat;
    const float* bs1a;
    const float* Ws1b; const float* bs1b;
    const float* Ws2a; const float* bs2a;
    const float* Ws2b; const float* bs2b;
    const float* Wc1a; const float* bc1a;
    const float* Wc1b; const float* bc1b;
    const float* Wc2a; const float* bc2a;
    const float* Wc2b; const float* bc2b;
    const float* Wd;   const float* bd;
    float* out;
    int partials;
};

// one stage: out[256 x N] = act(A[256 x K] @ B[K x N] + bias)
// 32x32 tiles; block covers tile (bid/nct, bid%nct); idle blocks return.
__device__ __forceinline__ void stage_gemm(const float* __restrict__ A,
                                           const float* __restrict__ B,
                                           const float* __restrict__ bias,
                                           float* __restrict__ out,
                                           int K, int N, int act,
                                           float* As /*32x33 [k][r]*/,
                                           float* Bs /*32x36 [k][c]*/) {
    const int t = threadIdx.x;
    const int nct = N >> 5;
    if ((int)blockIdx.x >= (nct << 3)) return;
    const int r0 = ((int)blockIdx.x / nct) * 32;
    const int c0 = ((int)blockIdx.x % nct) * 32;
    const int lrow = t >> 3;        // 0..31
    const int lk4  = (t & 7) * 4;   // 0,4,...,28
    const int tx = t & 15, ty = t >> 4;

    float a00 = 0.f, a01 = 0.f, a10 = 0.f, a11 = 0.f;
    for (int kb = 0; kb < K; kb += 32) {
        __syncthreads();
        float4 av = *(const float4*)&A[(size_t)(r0 + lrow) * K + kb + lk4];
        As[(lk4 + 0) * 33 + lrow] = av.x;
        As[(lk4 + 1) * 33 + lrow] = av.y;
        As[(lk4 + 2) * 33 + lrow] = av.z;
        As[(lk4 + 3) * 33 + lrow] = av.w;
        *(float4*)&Bs[lrow * 36 + lk4] =
            *(const float4*)&B[(size_t)(kb + lrow) * N + c0 + lk4];
        __syncthreads();
        #pragma unroll
        for (int kk = 0; kk < 32; ++kk) {
            float x0 = As[kk * 33 + ty * 2];
            float x1 = As[kk * 33 + ty * 2 + 1];
            float b0 = Bs[kk * 36 + tx * 2];
            float b1 = Bs[kk * 36 + tx * 2 + 1];
            a00 = fmaf(x0, b0, a00); a01 = fmaf(x0, b1, a01);
            a10 = fmaf(x1, b0, a10); a11 = fmaf(x1, b1, a11);
        }
    }
    const int r = r0 + ty * 2, c = c0 + tx * 2;
    float bb0 = bias ? bias[c] : 0.f, bb1 = bias ? bias[c + 1] : 0.f;
    float v00 = a00 + bb0, v01 = a01 + bb1, v10 = a10 + bb0, v11 = a11 + bb1;
    if (act) {
        v00 = fmaxf(v00, 0.f); v01 = fmaxf(v01, 0.f);
        v10 = fmaxf(v10, 0.f); v11 = fmaxf(v11, 0.f);
    }
    out[(size_t)r * N + c]           = v00;
    out[(size_t)r * N + c + 1]       = v01;
    out[(size_t)(r + 1) * N + c]     = v10;
    out[(size_t)(r + 1) * N + c + 1] = v11;
}

__device__ __forceinline__ float sigmoidf(float x) {
    return 1.0f / (1.0f + expf(-x));
}

__global__ __launch_bounds__(256)
void k_chain(ChainArgs a) {
    __shared__ float As[32 * 33];
    __shared__ float Bs[32 * 36];
    __shared__ float red[4];
    cg::grid_group g = cg::this_grid();
    const int t = threadIdx.x;

    // S0: reduce split-K partials -> Y1
    if (a.partials) {
        unsigned gtid = blockIdx.x * 256 + t;
        if (gtid < 32768) {
            const float4* pp = (const float4*)a.Y1p;
            float4 s = pp[gtid];
            #pragma unroll 8
            for (int z = 1; z < SPLITK; ++z) {
                float4 v = pp[(size_t)z * 32768 + gtid];
                s.x += v.x; s.y += v.y; s.z += v.z; s.w += v.w;
            }
            ((float4*)a.Y1)[gtid] = s;
        }
    }
    g.sync();

    // featurizer conv1
    stage_gemm(a.P,    a.Y1,   a.bs1a, a.bufA, 256, 512, 1, As, Bs); g.sync(); // t1
    stage_gemm(a.bufA, a.Ws1b, a.bs1b, a.bufB, 512, 512, 1, As, Bs); g.sync(); // h1r
    // featurizer conv2
    stage_gemm(a.P,    a.bufB, nullptr, a.bufA, 256, 512, 0, As, Bs); g.sync(); // A2
    stage_gemm(a.bufA, a.Ws2a, a.bs2a,  a.bufB, 512, 256, 1, As, Bs); g.sync(); // t2
    stage_gemm(a.bufB, a.Ws2b, a.bs2b,  a.feat, 256, 256, 0, As, Bs); g.sync(); // feat
    // scorer conv1
    stage_gemm(a.P,    a.feat, nullptr, a.bufA, 256, 256, 0, As, Bs); g.sync(); // A3
    stage_gemm(a.bufA, a.Wc1a, a.bc1a,  a.bufB, 256, 512, 1, As, Bs); g.sync(); // t3
    stage_gemm(a.bufB, a.Wc1b, a.bc1b,  a.bufA, 512, 512, 1, As, Bs); g.sync(); // s1r

    // scorer conv2 reassociated: u = s1r @ Wc2a  [256]
    if (blockIdx.x < 256) {
        int r = blockIdx.x;
        float s = a.bufA[(size_t)r * 512 + t] * a.Wc2a[t]
                + a.bufA[(size_t)r * 512 + 256 + t] * a.Wc2a[256 + t];
        #pragma unroll
        for (int off = 32; off; off >>= 1) s += __shfl_down(s, off, 64);
        if ((t & 63) == 0) red[t >> 6] = s;
        __syncthreads();
        if (t == 0) a.bufB[r] = red[0] + red[1] + red[2] + red[3];
    }
    g.sync();

    // region = sigmoid(relu(P@u + bc2a) * Wc2b + bc2b); dementia head in block 0
    if (blockIdx.x < 256) {
        int r = blockIdx.x;
        float s = a.P[r * 256 + t] * a.bufB[t];
        #pragma unroll
        for (int off = 32; off; off >>= 1) s += __shfl_down(s, off, 64);
        if ((t & 63) == 0) red[t >> 6] = s;
        __syncthreads();
        if (t == 0) {
            float h2 = fmaxf(red[0] + red[1] + red[2] + red[3] + a.bc2a[0], 0.f);
            a.out[1 + r] = sigmoidf(h2 * a.Wc2b[0] + a.bc2b[0]);
        }
        if (blockIdx.x == 0) {
            __syncthreads();
            float d = 0.f;
            for (int i = t; i < N_NODES * L_DIM; i += 256) d += a.feat[i] * a.Wd[i];
            #pragma unroll
            for (int off = 32; off; off >>= 1) d += __shfl_down(d, off, 64);
            if ((t & 63) == 0) red[t >> 6] = d;
            __syncthreads();
            if (t == 0)
                a.out[0] = sigmoidf(red[0] + red[1] + red[2] + red[3] + a.bd[0]);
        }
    }
}

extern "C" void kernel_launch(void* const* d_in, const int* in_sizes, int n_in,
                              void* d_out, int out_size, void* d_ws, size_t ws_size,
                              hipStream_t stream) {
    const float* x    = (const float*)d_in[0];
    const int*   idx  = (const int*)d_in[1];
    const float* Ws1a = (const float*)d_in[3];
    ChainArgs a;
    a.bs1a = (const float*)d_in[4];
    a.Ws1b = (const float*)d_in[5];  a.bs1b = (const float*)d_in[6];
    a.Ws2a = (const float*)d_in[7];  a.bs2a = (const float*)d_in[8];
    a.Ws2b = (const float*)d_in[9];  a.bs2b = (const float*)d_in[10];
    a.Wc1a = (const float*)d_in[11]; a.bc1a = (const float*)d_in[12];
    a.Wc1b = (const float*)d_in[13]; a.bc1b = (const float*)d_in[14];
    a.Wc2a = (const float*)d_in[15]; a.bc2a = (const float*)d_in[16];
    a.Wc2b = (const float*)d_in[17]; a.bc2b = (const float*)d_in[18];
    a.Wd   = (const float*)d_in[19]; a.bd   = (const float*)d_in[20];
    a.out  = (float*)d_out;
    const int E = in_sizes[1] / 2;

    float* w    = (float*)d_ws;
    float* P    = w;                  // 65536
    float* Y1   = P + 65536;          // 131072
    float* bufA = Y1 + 131072;        // 131072
    float* bufB = bufA + 131072;      // 131072
    float* feat = bufB + 131072;      // 65536
    float* Y1p  = feat + 65536;       // SPLITK * 131072
    const size_t need_full =
        (size_t)(65536 + 3 * 131072 + 65536 + (size_t)SPLITK * 131072) * 4;
    const int partials = (ws_size >= need_full) ? 1 : 0;

    a.P = P; a.Y1 = Y1; a.Y1p = Y1p;
    a.bufA = bufA; a.bufB = bufB; a.feat = feat;
    a.partials = partials;

    // adjacency P = I + C
    k_init_P<<<256, 256, 0, stream>>>(P);
    k_count_edges<<<(E + 255) / 256, 256, 0, stream>>>(idx, E, P);

    // Y1 = x @ Ws1a   (the only big GEMM; P@(x@W) == (P@x)@W)
    if (partials) {
        k_gemm_big<false><<<dim3(4, 2, SPLITK), 256, 0, stream>>>(x, Ws1a, Y1p);
    } else {
        k_zero<<<512, 256, 0, stream>>>(Y1, N_NODES * H_DIM);
        k_gemm_big<true><<<dim3(4, 2, SPLITK), 256, 0, stream>>>(x, Ws1a, Y1);
    }

    // everything else: one cooperative kernel with grid syncs between stages
    void* kp[] = { (void*)&a };
    hipLaunchCooperativeKernel((const void*)k_chain, dim3(256), dim3(256),
                               kp, 0, stream);
}

// Round 3
// 562.077 us; speedup vs baseline: 1.3065x; 1.3065x over previous
//
#include <hip/hip_runtime.h>
#include <math.h>

#define N_NODES 256
#define T_DIM   30000
#define H_DIM   512
#define L_DIM   256

#define KC      480   // per-split K chunk (mult of 16; 64*480 >= 30000)
#define SPLITK  64
#define NB      128   // chain blocks; 2 rows each

// ---------------- P = I + C ----------------
__global__ void k_init_P(float* P, unsigned* sync) {
    int t = blockIdx.x * blockDim.x + threadIdx.x; // 65536 threads
    P[t] = ((t >> 8) == (t & 255)) ? 1.0f : 0.0f;
    if (t < 8) sync[t] = 0u;   // cnt, gen, dem, pad
}

__global__ void k_count_edges(const int* __restrict__ idx, int E, float* P) {
    int e = blockIdx.x * blockDim.x + threadIdx.x;
    if (e < E) {
        int s = idx[e];
        int d = idx[E + e];
        atomicAdd(&P[d * N_NODES + s], 1.0f);
    }
}

__global__ void k_zero(float* p, int n) {
    int t = blockIdx.x * blockDim.x + threadIdx.x;
    if (t < n) p[t] = 0.0f;
}

// ---------------- big GEMM: Y1 = x @ Ws1a ---------------- (unchanged from R2)
template<bool ATOMIC>
__global__ __launch_bounds__(256)
void k_gemm_big(const float* __restrict__ x, const float* __restrict__ W,
                float* __restrict__ outp) {
    __shared__ float xs[16 * 140];
    __shared__ float ws[16 * 132];

    const int t  = threadIdx.x;
    const int bx = blockIdx.x;
    const int by = blockIdx.y;
    const int z  = blockIdx.z;
    const int rowBase = by * 128;
    const int colBase = bx * 128;
    const int kb0  = z * KC;
    const int kend = min(kb0 + KC, T_DIM);
    const int nchunk = (kend > kb0) ? ((kend - kb0) >> 4) : 0;

    const int lr  = t >> 2;
    const int lkq = (t & 3) * 4;
    const int wkk = t >> 5;
    const int wcq = (t & 31) * 4;
    const int tx  = t & 15, ty = t >> 4;

    float acc[8][8];
    #pragma unroll
    for (int i = 0; i < 8; ++i)
        #pragma unroll
        for (int j = 0; j < 8; ++j) acc[i][j] = 0.0f;

    if (nchunk > 0) {
        float4 xa, xb, wa, wb;
        {
            const float* xp = x + (size_t)(rowBase + lr) * T_DIM + kb0 + lkq;
            xa = *(const float4*)xp;
            xb = *(const float4*)(xp + (size_t)64 * T_DIM);
            const float* wp = W + (size_t)(kb0 + wkk) * H_DIM + colBase + wcq;
            wa = *(const float4*)wp;
            wb = *(const float4*)(wp + 8 * H_DIM);
        }

        for (int c = 0; c < nchunk; ++c) {
            __syncthreads();
            xs[(lkq + 0) * 140 + lr] = xa.x;
            xs[(lkq + 1) * 140 + lr] = xa.y;
            xs[(lkq + 2) * 140 + lr] = xa.z;
            xs[(lkq + 3) * 140 + lr] = xa.w;
            xs[(lkq + 0) * 140 + lr + 64] = xb.x;
            xs[(lkq + 1) * 140 + lr + 64] = xb.y;
            xs[(lkq + 2) * 140 + lr + 64] = xb.z;
            xs[(lkq + 3) * 140 + lr + 64] = xb.w;
            *(float4*)&ws[wkk * 132 + wcq]       = wa;
            *(float4*)&ws[(wkk + 8) * 132 + wcq] = wb;
            __syncthreads();

            if (c + 1 < nchunk) {
                int kb = kb0 + (c + 1) * 16;
                const float* xp = x + (size_t)(rowBase + lr) * T_DIM + kb + lkq;
                xa = *(const float4*)xp;
                xb = *(const float4*)(xp + (size_t)64 * T_DIM);
                const float* wp = W + (size_t)(kb + wkk) * H_DIM + colBase + wcq;
                wa = *(const float4*)wp;
                wb = *(const float4*)(wp + 8 * H_DIM);
            }

            #pragma unroll
            for (int kk = 0; kk < 16; ++kk) {
                float a[8], b[8];
                *(float4*)&a[0] = *(const float4*)&xs[kk * 140 + ty * 8];
                *(float4*)&a[4] = *(const float4*)&xs[kk * 140 + ty * 8 + 4];
                *(float4*)&b[0] = *(const float4*)&ws[kk * 132 + tx * 8];
                *(float4*)&b[4] = *(const float4*)&ws[kk * 132 + tx * 8 + 4];
                #pragma unroll
                for (int i = 0; i < 8; ++i)
                    #pragma unroll
                    for (int j = 0; j < 8; ++j)
                        acc[i][j] = fmaf(a[i], b[j], acc[i][j]);
            }
        }
    }

    if (ATOMIC) {
        if (nchunk == 0) return;
        #pragma unroll
        for (int i = 0; i < 8; ++i) {
            int r = rowBase + ty * 8 + i;
            #pragma unroll
            for (int j = 0; j < 8; ++j)
                atomicAdd(&outp[r * H_DIM + colBase + tx * 8 + j], acc[i][j]);
        }
    } else {
        float* op = outp + (size_t)z * (N_NODES * H_DIM);
        #pragma unroll
        for (int i = 0; i < 8; ++i) {
            int r = rowBase + ty * 8 + i;
            *(float4*)&op[r * H_DIM + colBase + tx * 8]     = *(float4*)&acc[i][0];
            *(float4*)&op[r * H_DIM + colBase + tx * 8 + 4] = *(float4*)&acc[i][4];
        }
    }
}

// ---------------- fused chain with custom grid barrier ----------------
struct ChainArgs {
    const float* P;
    const float* Y1p;
    float* Y1;
    float* h1r;
    float* feat;
    float* u;
    unsigned* cnt; unsigned* gen; float* dem;
    const float* bs1a;
    const float* Ws1b; const float* bs1b;
    const float* Ws2a; const float* bs2a;
    const float* Ws2b; const float* bs2b;
    const float* Wc1a; const float* bc1a;
    const float* Wc1b; const float* bc1b;
    const float* Wc2a; const float* bc2a;
    const float* Wc2b; const float* bc2b;
    const float* Wd;   const float* bd;
    float* out;
    int partials;
};

__device__ __forceinline__ void gbar(unsigned* cnt, unsigned* gen, unsigned nb) {
    __threadfence();          // release this thread's stores to device scope
    __syncthreads();
    if (threadIdx.x == 0) {
        unsigned g = __hip_atomic_load(gen, __ATOMIC_RELAXED, __HIP_MEMORY_SCOPE_AGENT);
        unsigned arrived = __hip_atomic_fetch_add(cnt, 1u, __ATOMIC_ACQ_REL,
                                                  __HIP_MEMORY_SCOPE_AGENT);
        if (arrived == nb - 1u) {
            __hip_atomic_store(cnt, 0u, __ATOMIC_RELAXED, __HIP_MEMORY_SCOPE_AGENT);
            __hip_atomic_fetch_add(gen, 1u, __ATOMIC_RELEASE, __HIP_MEMORY_SCOPE_AGENT);
        } else {
            while (__hip_atomic_load(gen, __ATOMIC_ACQUIRE,
                                     __HIP_MEMORY_SCOPE_AGENT) == g) {
                __builtin_amdgcn_s_sleep(1);
            }
        }
    }
    __syncthreads();
    __threadfence();          // acquire: discard stale cached lines
}

__device__ __forceinline__ float block_reduce(float v, float* red) {
    #pragma unroll
    for (int off = 32; off; off >>= 1) v += __shfl_down(v, off, 64);
    __syncthreads();
    if ((threadIdx.x & 63) == 0) red[threadIdx.x >> 6] = v;
    __syncthreads();
    return red[0] + red[1] + red[2] + red[3];
}

__device__ __forceinline__ float sigmoidf(float x) {
    return 1.0f / (1.0f + expf(-x));
}

__global__ __launch_bounds__(256)
void k_chain(ChainArgs a) {
    __shared__ float prow[2][256];
    __shared__ float buf512[2][512];
    __shared__ float buf256[2][256];
    __shared__ float red[4];
    const int t = threadIdx.x;
    const int b = blockIdx.x;
    const int r0 = 2 * b, r1 = 2 * b + 1;

    // phase 0: reduce split-K partials -> Y1 (32768 float4 over 32768 threads)
    if (a.partials) {
        unsigned gtid = b * 256 + t;
        const float4* pp = (const float4*)a.Y1p;
        float4 s = pp[gtid];
        #pragma unroll 8
        for (int z = 1; z < SPLITK; ++z) {
            float4 v = pp[(size_t)z * 32768 + gtid];
            s.x += v.x; s.y += v.y; s.z += v.z; s.w += v.w;
        }
        ((float4*)a.Y1)[gtid] = s;
    }
    prow[0][t] = a.P[r0 * 256 + t];
    prow[1][t] = a.P[r1 * 256 + t];
    gbar(a.cnt, a.gen, NB);                                   // B1

    // ---- phase 1: t1 = relu(P@Y1 + bs1a); h1r = relu(t1@Ws1b + bs1b) ----
    {
        float a00 = 0.f, a01 = 0.f, a10 = 0.f, a11 = 0.f;
        #pragma unroll 8
        for (int k = 0; k < 256; ++k) {
            float y0 = a.Y1[k * 512 + t];
            float y1 = a.Y1[k * 512 + t + 256];
            float p0 = prow[0][k], p1 = prow[1][k];
            a00 = fmaf(p0, y0, a00); a01 = fmaf(p0, y1, a01);
            a10 = fmaf(p1, y0, a10); a11 = fmaf(p1, y1, a11);
        }
        float b0 = a.bs1a[t], b1 = a.bs1a[t + 256];
        buf512[0][t]       = fmaxf(a00 + b0, 0.f);
        buf512[0][t + 256] = fmaxf(a01 + b1, 0.f);
        buf512[1][t]       = fmaxf(a10 + b0, 0.f);
        buf512[1][t + 256] = fmaxf(a11 + b1, 0.f);
    }
    __syncthreads();
    {
        float a00 = 0.f, a01 = 0.f, a10 = 0.f, a11 = 0.f;
        #pragma unroll 4
        for (int k = 0; k < 512; ++k) {
            float w0 = a.Ws1b[k * 512 + t];
            float w1 = a.Ws1b[k * 512 + t + 256];
            float x0 = buf512[0][k], x1 = buf512[1][k];
            a00 = fmaf(x0, w0, a00); a01 = fmaf(x0, w1, a01);
            a10 = fmaf(x1, w0, a10); a11 = fmaf(x1, w1, a11);
        }
        float b0 = a.bs1b[t], b1 = a.bs1b[t + 256];
        a.h1r[r0 * 512 + t]       = fmaxf(a00 + b0, 0.f);
        a.h1r[r0 * 512 + t + 256] = fmaxf(a01 + b1, 0.f);
        a.h1r[r1 * 512 + t]       = fmaxf(a10 + b0, 0.f);
        a.h1r[r1 * 512 + t + 256] = fmaxf(a11 + b1, 0.f);
    }
    gbar(a.cnt, a.gen, NB);                                   // B2

    // ---- phase 2: A2 = P@h1r; t2 = relu(A2@Ws2a+b); feat = t2@Ws2b+b ----
    {
        float a00 = 0.f, a01 = 0.f, a10 = 0.f, a11 = 0.f;
        #pragma unroll 8
        for (int k = 0; k < 256; ++k) {
            float y0 = a.h1r[k * 512 + t];
            float y1 = a.h1r[k * 512 + t + 256];
            float p0 = prow[0][k], p1 = prow[1][k];
            a00 = fmaf(p0, y0, a00); a01 = fmaf(p0, y1, a01);
            a10 = fmaf(p1, y0, a10); a11 = fmaf(p1, y1, a11);
        }
        buf512[0][t]       = a00;
        buf512[0][t + 256] = a01;
        buf512[1][t]       = a10;
        buf512[1][t + 256] = a11;
    }
    __syncthreads();
    {
        float s0 = 0.f, s1 = 0.f;
        #pragma unroll 8
        for (int k = 0; k < 512; ++k) {
            float w = a.Ws2a[k * 256 + t];
            s0 = fmaf(buf512[0][k], w, s0);
            s1 = fmaf(buf512[1][k], w, s1);
        }
        float bb = a.bs2a[t];
        buf256[0][t] = fmaxf(s0 + bb, 0.f);
        buf256[1][t] = fmaxf(s1 + bb, 0.f);
    }
    __syncthreads();
    {
        float s0 = 0.f, s1 = 0.f;
        #pragma unroll 8
        for (int k = 0; k < 256; ++k) {
            float w = a.Ws2b[k * 256 + t];
            s0 = fmaf(buf256[0][k], w, s0);
            s1 = fmaf(buf256[1][k], w, s1);
        }
        float bb = a.bs2b[t];
        float f0 = s0 + bb, f1 = s1 + bb;
        a.feat[r0 * 256 + t] = f0;
        a.feat[r1 * 256 + t] = f1;
        float p = f0 * a.Wd[r0 * 256 + t] + f1 * a.Wd[r1 * 256 + t];
        float tot = block_reduce(p, red);
        if (t == 0) atomicAdd(a.dem, tot);
    }
    gbar(a.cnt, a.gen, NB);                                   // B3

    // ---- phase 3: A3 = P@feat; t3 = relu(A3@Wc1a+b); s1r = relu(t3@Wc1b+b);
    //               u = s1r @ Wc2a ----
    {
        float s0 = 0.f, s1 = 0.f;
        #pragma unroll 8
        for (int k = 0; k < 256; ++k) {
            float f = a.feat[k * 256 + t];
            s0 = fmaf(prow[0][k], f, s0);
            s1 = fmaf(prow[1][k], f, s1);
        }
        buf256[0][t] = s0;
        buf256[1][t] = s1;
    }
    __syncthreads();
    {
        float a00 = 0.f, a01 = 0.f, a10 = 0.f, a11 = 0.f;
        #pragma unroll 8
        for (int k = 0; k < 256; ++k) {
            float w0 = a.Wc1a[k * 512 + t];
            float w1 = a.Wc1a[k * 512 + t + 256];
            float x0 = buf256[0][k], x1 = buf256[1][k];
            a00 = fmaf(x0, w0, a00); a01 = fmaf(x0, w1, a01);
            a10 = fmaf(x1, w0, a10); a11 = fmaf(x1, w1, a11);
        }
        float b0 = a.bc1a[t], b1 = a.bc1a[t + 256];
        // need buf512 free: last read was phase-2 t2 stage, synced since
        buf512[0][t]       = fmaxf(a00 + b0, 0.f);
        buf512[0][t + 256] = fmaxf(a01 + b1, 0.f);
        buf512[1][t]       = fmaxf(a10 + b0, 0.f);
        buf512[1][t + 256] = fmaxf(a11 + b1, 0.f);
    }
    __syncthreads();
    {
        float a00 = 0.f, a01 = 0.f, a10 = 0.f, a11 = 0.f;
        #pragma unroll 4
        for (int k = 0; k < 512; ++k) {
            float w0 = a.Wc1b[k * 512 + t];
            float w1 = a.Wc1b[k * 512 + t + 256];
            float x0 = buf512[0][k], x1 = buf512[1][k];
            a00 = fmaf(x0, w0, a00); a01 = fmaf(x0, w1, a01);
            a10 = fmaf(x1, w0, a10); a11 = fmaf(x1, w1, a11);
        }
        float b0 = a.bc1b[t], b1 = a.bc1b[t + 256];
        float s00 = fmaxf(a00 + b0, 0.f);
        float s01 = fmaxf(a01 + b1, 0.f);
        float s10 = fmaxf(a10 + b0, 0.f);
        float s11 = fmaxf(a11 + b1, 0.f);
        float w0 = a.Wc2a[t], w1 = a.Wc2a[t + 256];
        float up0 = s00 * w0 + s01 * w1;
        float up1 = s10 * w0 + s11 * w1;
        float u0 = block_reduce(up0, red);
        float u1 = block_reduce(up1, red);
        if (t == 0) { a.u[r0] = u0; a.u[r1] = u1; }
    }
    gbar(a.cnt, a.gen, NB);                                   // B4

    // ---- phase 4: v = P@u; scores; dementia head ----
    {
        float uv = a.u[t];
        float v0 = block_reduce(prow[0][t] * uv, red);
        float v1 = block_reduce(prow[1][t] * uv, red);
        if (t == 0) {
            float c2a = a.bc2a[0], c2bW = a.Wc2b[0], c2bb = a.bc2b[0];
            a.out[1 + r0] = sigmoidf(fmaxf(v0 + c2a, 0.f) * c2bW + c2bb);
            a.out[1 + r1] = sigmoidf(fmaxf(v1 + c2a, 0.f) * c2bW + c2bb);
            if (b == 0) a.out[0] = sigmoidf(*a.dem + a.bd[0]);
        }
    }
}

extern "C" void kernel_launch(void* const* d_in, const int* in_sizes, int n_in,
                              void* d_out, int out_size, void* d_ws, size_t ws_size,
                              hipStream_t stream) {
    const float* x    = (const float*)d_in[0];
    const int*   idx  = (const int*)d_in[1];
    const float* Ws1a = (const float*)d_in[3];
    ChainArgs a;
    a.bs1a = (const float*)d_in[4];
    a.Ws1b = (const float*)d_in[5];  a.bs1b = (const float*)d_in[6];
    a.Ws2a = (const float*)d_in[7];  a.bs2a = (const float*)d_in[8];
    a.Ws2b = (const float*)d_in[9];  a.bs2b = (const float*)d_in[10];
    a.Wc1a = (const float*)d_in[11]; a.bc1a = (const float*)d_in[12];
    a.Wc1b = (const float*)d_in[13]; a.bc1b = (const float*)d_in[14];
    a.Wc2a = (const float*)d_in[15]; a.bc2a = (const float*)d_in[16];
    a.Wc2b = (const float*)d_in[17]; a.bc2b = (const float*)d_in[18];
    a.Wd   = (const float*)d_in[19]; a.bd   = (const float*)d_in[20];
    a.out  = (float*)d_out;
    const int E = in_sizes[1] / 2;

    float* w    = (float*)d_ws;
    float* P    = w;                  // 65536
    float* Y1   = P + 65536;          // 131072
    float* h1r  = Y1 + 131072;        // 131072
    float* feat = h1r + 131072;       // 65536
    float* u    = feat + 65536;       // 256
    float* syncf = u + 256;           // 64 (cnt, gen, dem, pad)
    float* Y1p  = syncf + 64;         // SPLITK * 131072
    const size_t need_full =
        (size_t)(65536 + 2 * 131072 + 65536 + 256 + 64 + (size_t)SPLITK * 131072) * 4;
    const int partials = (ws_size >= need_full) ? 1 : 0;

    a.P = P; a.Y1 = Y1; a.Y1p = Y1p;
    a.h1r = h1r; a.feat = feat; a.u = u;
    a.cnt = (unsigned*)syncf; a.gen = ((unsigned*)syncf) + 1;
    a.dem = syncf + 2;
    a.partials = partials;

    // adjacency P = I + C; zero barrier state + dementia accumulator
    k_init_P<<<256, 256, 0, stream>>>(P, (unsigned*)syncf);
    k_count_edges<<<(E + 255) / 256, 256, 0, stream>>>(idx, E, P);

    // Y1 = x @ Ws1a   (P@(x@W) == (P@x)@W)
    if (partials) {
        k_gemm_big<false><<<dim3(4, 2, SPLITK), 256, 0, stream>>>(x, Ws1a, Y1p);
    } else {
        k_zero<<<512, 256, 0, stream>>>(Y1, N_NODES * H_DIM);
        k_gemm_big<true><<<dim3(4, 2, SPLITK), 256, 0, stream>>>(x, Ws1a, Y1);
    }

    // fused chain: 128 persistent blocks, 4 custom grid barriers
    k_chain<<<NB, 256, 0, stream>>>(a);
}